// Round 1
// baseline (531.779 us; speedup 1.0000x reference)
//
#include <hip/hip_runtime.h>

#define BB   16      // batch
#define NC   1024    // candidates per query row
#define QL   32      // query tokens
#define HD   128     // embed dim
#define DLN  64      // doc tokens per doc

// ---------------------------------------------------------------------------
// K1: pids = emb2pid[topk]; validate; per-row descending bitonic sort; dedup.
// One block (1024 threads) per batch row. Mirrors _dedup_pids exactly.
// ---------------------------------------------------------------------------
__global__ __launch_bounds__(1024) void k_gather_sort_dedup(
    const int* __restrict__ topk, const int* __restrict__ emb2pid,
    int n_emb, int n_docs, int* __restrict__ pids_out)
{
    const int b = blockIdx.x;
    const int t = threadIdx.x;
    __shared__ int s[NC];

    int idx = topk[b * NC + t];
    int pid = (idx >= 0 && idx < n_emb) ? emb2pid[idx] : -1;
    if (pid < 0 || pid >= n_docs) pid = -1;
    s[t] = pid;
    __syncthreads();

    // Bitonic sort, final order DESCENDING (mirror of the standard ascending net).
    for (int k2 = 2; k2 <= NC; k2 <<= 1) {
        for (int j = k2 >> 1; j > 0; j >>= 1) {
            int ixj = t ^ j;
            if (ixj > t) {
                int a = s[t], c = s[ixj];
                bool desc = ((t & k2) == 0);
                if (desc ? (a < c) : (a > c)) { s[t] = c; s[ixj] = a; }
            }
            __syncthreads();
        }
    }
    int v = s[t];
    pids_out[b * NC + t] = (t > 0 && v == s[t - 1]) ? -1 : v;
}

// ---------------------------------------------------------------------------
// K2: scores[b][n] = mean_q max_d  dot(q[b,q,:], vectors[pid,d,:])
// One 256-thread block per (b,n). Doc tile staged in padded LDS.
// f64 accumulation for rank-stability vs the f64 numpy reference.
// Thread map: tq = t&15 -> q rows {2tq, 2tq+1}; td = t>>4 -> d rows {4td..4td+3}
// ---------------------------------------------------------------------------
#define DPAD (HD + 4)   // 132 floats: rows td*4+j land on 2 distinct banks max

__global__ __launch_bounds__(256) void k_scores(
    const float* __restrict__ q,     // [BB][QL][HD]
    const float* __restrict__ vecs,  // [n_docs][DLN][HD]
    const int* __restrict__ pids,    // [BB][NC]
    float* __restrict__ scores)      // [BB][NC]
{
    const int n = blockIdx.x, b = blockIdx.y;
    const int t = threadIdx.x;
    const int pid = pids[b * NC + n];
    if (pid < 0) {
        if (t == 0) scores[b * NC + n] = -__builtin_inff();
        return;
    }

    __shared__ float sdoc[DLN][DPAD];
    __shared__ double red[4][16][2];

    // Stage doc tile (64x128 f32 = 32KB) coalesced, float4.
    {
        const float4* src = (const float4*)(vecs + (size_t)pid * DLN * HD);
        for (int i = t; i < DLN * HD / 4; i += 256) {
            float4 v = src[i];
            int d  = i >> 5;            // 32 float4 per row
            int h4 = (i & 31) << 2;
            *(float4*)&sdoc[d][h4] = v;
        }
    }
    __syncthreads();

    const int tq = t & 15;
    const int td = t >> 4;
    const float* qb = q + ((size_t)b * QL + tq * 2) * HD;

    double acc[2][4] = {};
    for (int h = 0; h < HD; h += 4) {
        float4 a0 = *(const float4*)(qb + h);
        float4 a1 = *(const float4*)(qb + HD + h);
        float4 bv[4];
#pragma unroll
        for (int j = 0; j < 4; ++j)
            bv[j] = *(const float4*)&sdoc[td * 4 + j][h];
#pragma unroll
        for (int j = 0; j < 4; ++j) {
            acc[0][j] += (double)a0.x * bv[j].x + (double)a0.y * bv[j].y
                       + (double)a0.z * bv[j].z + (double)a0.w * bv[j].w;
            acc[1][j] += (double)a1.x * bv[j].x + (double)a1.y * bv[j].y
                       + (double)a1.z * bv[j].z + (double)a1.w * bv[j].w;
        }
    }

    // Per-thread max over its 4 d's, per q row.
    double m0 = fmax(fmax(acc[0][0], acc[0][1]), fmax(acc[0][2], acc[0][3]));
    double m1 = fmax(fmax(acc[1][0], acc[1][1]), fmax(acc[1][2], acc[1][3]));

    // Max across the wave's 4 td-groups (lanes l, l^16, l^32, l^48 share tq).
    m0 = fmax(m0, __shfl_xor(m0, 16)); m1 = fmax(m1, __shfl_xor(m1, 16));
    m0 = fmax(m0, __shfl_xor(m0, 32)); m1 = fmax(m1, __shfl_xor(m1, 32));

    const int wave = t >> 6;
    if ((t & 63) < 16) { red[wave][tq][0] = m0; red[wave][tq][1] = m1; }
    __syncthreads();

    if (t < 32) {
        int qi = t;                      // q row index 0..31
        int g = qi >> 1, i = qi & 1;
        double v = fmax(fmax(red[0][g][i], red[1][g][i]),
                        fmax(red[2][g][i], red[3][g][i]));
        // Sum over 32 q rows (lanes 0..31 of wave 0).
        v += __shfl_xor(v, 1);
        v += __shfl_xor(v, 2);
        v += __shfl_xor(v, 4);
        v += __shfl_xor(v, 8);
        v += __shfl_xor(v, 16);
        if (t == 0) scores[b * NC + n] = (float)(v * (1.0 / 32.0));
    }
}

// ---------------------------------------------------------------------------
// K3: per-row stable top-k via full bitonic sort of (score desc, idx asc).
// Reproduces jax.lax.top_k ordering. Writes pids (as float) then scores.
// ---------------------------------------------------------------------------
__global__ __launch_bounds__(1024) void k_topk(
    const float* __restrict__ scores, const int* __restrict__ pids,
    float* __restrict__ out, int k)
{
    const int b = blockIdx.x;
    const int t = threadIdx.x;
    __shared__ float ss[NC];
    __shared__ int   si[NC];

    ss[t] = scores[b * NC + t];
    si[t] = t;
    __syncthreads();

    for (int k2 = 2; k2 <= NC; k2 <<= 1) {
        for (int j = k2 >> 1; j > 0; j >>= 1) {
            int ixj = t ^ j;
            if (ixj > t) {
                float as = ss[t], bs = ss[ixj];
                int   ai = si[t], bi = si[ixj];
                bool a_first = (as > bs) || (as == bs && ai < bi);
                bool desc = ((t & k2) == 0);
                bool swap = desc ? !a_first : a_first;
                if (swap) { ss[t] = bs; si[t] = bi; ss[ixj] = as; si[ixj] = ai; }
            }
            __syncthreads();
        }
    }

    if (t < k) {
        out[b * k + t]           = (float)pids[b * NC + si[t]];  // top_pids
        out[BB * k + b * k + t]  = ss[t];                        // top_scores
    }
}

// ---------------------------------------------------------------------------
extern "C" void kernel_launch(void* const* d_in, const int* in_sizes, int n_in,
                              void* d_out, int out_size, void* d_ws, size_t ws_size,
                              hipStream_t stream)
{
    const float* q_vectors = (const float*)d_in[0];   // [16][32][128] f32
    const int*   topk_idx  = (const int*)d_in[1];     // [16][1024] i32
    const float* vectors   = (const float*)d_in[2];   // [20000][64][128] f32
    const int*   emb2pid   = (const int*)d_in[3];     // [1280000] i32

    const int n_emb  = in_sizes[3];
    const int n_docs = in_sizes[2] / (DLN * HD);
    const int k      = out_size / (2 * BB);           // 3200/(2*16) = 100

    int*   pids_ws   = (int*)d_ws;                                  // 64 KB
    float* scores_ws = (float*)((char*)d_ws + BB * NC * sizeof(int)); // 64 KB

    k_gather_sort_dedup<<<dim3(BB), dim3(NC), 0, stream>>>(
        topk_idx, emb2pid, n_emb, n_docs, pids_ws);

    k_scores<<<dim3(NC, BB), dim3(256), 0, stream>>>(
        q_vectors, vectors, pids_ws, scores_ws);

    k_topk<<<dim3(BB), dim3(NC), 0, stream>>>(
        scores_ws, pids_ws, (float*)d_out, k);
}